// Round 12
// baseline (242.258 us; speedup 1.0000x reference)
//
#include <hip/hip_runtime.h>
#include <hip/hip_bf16.h>
#include <math.h>

typedef unsigned int u32;
typedef unsigned short u16;
typedef __attribute__((ext_vector_type(4))) float f32x4;
typedef __attribute__((ext_vector_type(8))) short bf16x8;

#define DEV __device__ __forceinline__

DEV u16 f2bf(float f) {
  union { float f; u32 u; } v; v.f = f;
  u32 u = v.u;
  return (u16)((u + 0x7FFFu + ((u >> 16) & 1u)) >> 16);
}

DEV float bf2f(u16 h) {
  union { u32 u; float f; } v; v.u = (u32)h << 16;
  return v.f;
}

// v_cvt_pk_bf16_f32: lo = bf16(a), hi = bf16(b) (RNE)
DEV u32 pk2(float a, float b) {
  u32 r;
  asm("v_cvt_pk_bf16_f32 %0, %1, %2" : "=v"(r) : "v"(a), "v"(b));
  return r;
}

// ------------------------------------------------------------------
// Conv 5x5 (9->128) + BN(eval) + LeakyReLU(0.2) + 2D pos-enc
// Writes result to BOTH t0 (LN input) and attn (residual base).
// ------------------------------------------------------------------
__global__ __launch_bounds__(256) void k_conv(
    const float* __restrict__ x, const float* __restrict__ cw,
    const float* __restrict__ bng, const float* __restrict__ bnb,
    float* __restrict__ t0, float* __restrict__ attn)
{
  __shared__ float sinp[9 * 400];
  __shared__ float sw[225 * 16];
  const int t = threadIdx.x;
  const int tile = blockIdx.x, cg = blockIdx.y, b = blockIdx.z;
  const int ty0 = (tile / 5) * 16, tx0 = (tile % 5) * 16;

  for (int i = t; i < 3600; i += 256) {
    int ci = i / 400, rem = i % 400, r = rem / 20, cc = rem % 20;
    int gy = ty0 + r - 2, gx = tx0 + cc - 2;
    float v = 0.f;
    if ((unsigned)gy < 80u && (unsigned)gx < 80u) {
      int c = ci % 3, tt = ci / 3;
      v = x[(((size_t)b * 3 + c) * 3 + tt) * 6400 + gy * 80 + gx];
    }
    sinp[i] = v;
  }
  for (int i = t; i < 3600; i += 256) {
    int c = i & 15, j = i >> 4;
    sw[i] = cw[(size_t)(cg * 16 + c) * 225 + j];
  }
  __syncthreads();

  const int lx = t & 15, ly = t >> 4;
  float acc[16];
#pragma unroll
  for (int c = 0; c < 16; c++) acc[c] = 0.f;

  for (int ci = 0; ci < 9; ci++) {
#pragma unroll
    for (int ky = 0; ky < 5; ky++) {
      const float* ro = &sinp[ci * 400 + (ly + ky) * 20 + lx];
#pragma unroll
      for (int kx = 0; kx < 5; kx++) {
        float v = ro[kx];
        const float4* w4 = (const float4*)&sw[(ci * 25 + ky * 5 + kx) * 16];
        float4 w0 = w4[0], w1 = w4[1], w2 = w4[2], w3 = w4[3];
        acc[0] += v * w0.x;  acc[1] += v * w0.y;  acc[2] += v * w0.z;  acc[3] += v * w0.w;
        acc[4] += v * w1.x;  acc[5] += v * w1.y;  acc[6] += v * w1.z;  acc[7] += v * w1.w;
        acc[8] += v * w2.x;  acc[9] += v * w2.y;  acc[10] += v * w2.z; acc[11] += v * w2.w;
        acc[12] += v * w3.x; acc[13] += v * w3.y; acc[14] += v * w3.z; acc[15] += v * w3.w;
      }
    }
  }

  const int gy = ty0 + ly, gx = tx0 + lx;
  const int n = gy * 80 + gx;
  const float rb = rsqrtf(1.f + 1e-5f);
  const float NEG_L = -logf(10000.f) / 32.f;
  float outv[16];
#pragma unroll
  for (int c = 0; c < 16; c++) {
    int co = cg * 16 + c;
    float v = acc[c] * rb * bng[co] + bnb[co];
    v = v > 0.f ? v : 0.2f * v;
    int j = (co < 64) ? co : co - 64;
    float pos = (co < 64) ? (float)gy : (float)gx;
    int k = j & 31;
    float ang = pos * __expf((float)k * NEG_L);
    v += (j < 32) ? __sinf(ang) : __cosf(ang);
    outv[c] = v;
  }
  const size_t base = ((size_t)b * 6400 + n) * 128 + cg * 16;
  float4* dst = (float4*)&t0[base];
  float4* dst2 = (float4*)&attn[base];
  const float4* src = (const float4*)outv;
  dst[0] = src[0]; dst[1] = src[1]; dst[2] = src[2]; dst[3] = src[3];
  dst2[0] = src[0]; dst2[1] = src[1]; dst2[2] = src[2]; dst2[3] = src[3];
}

// ------------------------------------------------------------------
// LayerNorm over last dim (128), fp32 in -> bf16 out. 1 wave = 1 token.
// ------------------------------------------------------------------
__global__ __launch_bounds__(256) void k_ln(
    const float* __restrict__ X, const float* __restrict__ g,
    const float* __restrict__ bta, u16* __restrict__ O)
{
  const int w = threadIdx.x >> 6, l = threadIdx.x & 63;
  const int tok = blockIdx.x * 4 + w;
  const float2 v = ((const float2*)(X + (size_t)tok * 128))[l];
  float s = v.x + v.y;
#pragma unroll
  for (int m = 1; m < 64; m <<= 1) s += __shfl_xor(s, m);
  const float mean = s * (1.f / 128.f);
  const float dx = v.x - mean, dy = v.y - mean;
  float q = dx * dx + dy * dy;
#pragma unroll
  for (int m = 1; m < 64; m <<= 1) q += __shfl_xor(q, m);
  const float rstd = rsqrtf(q * (1.f / 128.f) + 1e-5f);
  const float2 gg = ((const float2*)g)[l];
  const float2 bb = ((const float2*)bta)[l];
  const float o0 = dx * rstd * gg.x + bb.x;
  const float o1 = dy * rstd * gg.y + bb.y;
  ((u32*)O)[(size_t)tok * 64 + l] = (u32)f2bf(o0) | ((u32)f2bf(o1) << 16);
}

// ------------------------------------------------------------------
// Weight convert/transpose: fp32 [K][N] -> bf16 [N][K]
// ------------------------------------------------------------------
__global__ __launch_bounds__(256) void k_wconv_qkv(
    const float* __restrict__ wq, const float* __restrict__ wk,
    const float* __restrict__ wv, u16* __restrict__ o)
{
  const int z = blockIdx.y;
  const float* in = (z == 0) ? wq : (z == 1) ? wk : wv;
  u16* out = o + (size_t)z * 16384;
  const int i = blockIdx.x * 256 + threadIdx.x;
  const int n = i & 127, k = i >> 7;
  out[n * 128 + k] = f2bf(in[i]);
}

__global__ __launch_bounds__(256) void k_wt(
    const float* __restrict__ in, u16* __restrict__ out, int K, int N)
{
  const int i = blockIdx.x * 256 + threadIdx.x;
  if (i >= K * N) return;
  const int n = i % N, k = i / N;
  out[n * K + k] = f2bf(in[i]);
}

// ------------------------------------------------------------------
// Generic MFMA GEMM body
// ------------------------------------------------------------------
template <int KDIM, int NTILE, int EPI>
DEV void gemm_body(const u16* __restrict__ A, const u16* __restrict__ WT,
                   void* __restrict__ OUT, const float* __restrict__ bias,
                   const float* __restrict__ res, float scale, int bm)
{
  constexpr int PS = KDIM * 2 + 16;
  constexpr int KSTEPS = KDIM / 32;
  constexpr int CF = NTILE / 64;
  constexpr int CPR = KDIM * 2 / 16;
  __shared__ alignas(16) char As[64 * PS];
  __shared__ alignas(16) char Ws[NTILE * PS];
  const int t = threadIdx.x;
  {
    const uint4* g = (const uint4*)(A + (size_t)bm * 64 * KDIM);
    for (int i = t; i < 64 * CPR; i += 256) {
      int r = i / CPR, s = i - r * CPR;
      *(uint4*)(As + r * PS + s * 16) = g[i];
    }
    const uint4* gw = (const uint4*)WT;
    for (int i = t; i < NTILE * CPR; i += 256) {
      int r = i / CPR, s = i - r * CPR;
      *(uint4*)(Ws + r * PS + s * 16) = gw[i];
    }
  }
  __syncthreads();
  const int w = t >> 6, l = t & 63, lr = l & 15, lg = l >> 4;
  const int col0 = w * (NTILE / 4);
  f32x4 acc[4][CF] = {};
#pragma unroll
  for (int ks = 0; ks < KSTEPS; ks++) {
    const int koff = ks * 64 + lg * 16;
    bf16x8 a[4], bfr[CF];
#pragma unroll
    for (int rf = 0; rf < 4; rf++)
      a[rf] = *(const bf16x8*)(As + (rf * 16 + lr) * PS + koff);
#pragma unroll
    for (int cf = 0; cf < CF; cf++)
      bfr[cf] = *(const bf16x8*)(Ws + (col0 + cf * 16 + lr) * PS + koff);
#pragma unroll
    for (int rf = 0; rf < 4; rf++)
#pragma unroll
      for (int cf = 0; cf < CF; cf++)
        acc[rf][cf] = __builtin_amdgcn_mfma_f32_16x16x32_bf16(a[rf], bfr[cf], acc[rf][cf], 0, 0, 0);
  }
#pragma unroll
  for (int rf = 0; rf < 4; rf++) {
#pragma unroll
    for (int cf = 0; cf < CF; cf++) {
#pragma unroll
      for (int r = 0; r < 4; r++) {
        const int row = bm * 64 + rf * 16 + lg * 4 + r;
        const int col = col0 + cf * 16 + lr;
        float v = acc[rf][cf][r] * scale;
        if (EPI == 0) {
          ((u16*)OUT)[(size_t)row * NTILE + col] = f2bf(v);
        } else if (EPI == 1) {
          v += bias[col];
          v = 0.5f * v * (1.f + erff(v * 0.70710678118654752f));
          ((u16*)OUT)[(size_t)row * NTILE + col] = f2bf(v);
        } else {
          v += bias[col] + res[(size_t)row * NTILE + col];
          ((float*)OUT)[(size_t)row * NTILE + col] = v;
        }
      }
    }
  }
}

__global__ __launch_bounds__(256) void k_qkv(
    const u16* __restrict__ A, const u16* __restrict__ wT,
    u16* __restrict__ Q, u16* __restrict__ K, u16* __restrict__ V, float qscale)
{
  const int z = blockIdx.y;
  const u16* wt = wT + (size_t)z * 16384;
  u16* o = (z == 0) ? Q : (z == 1) ? K : V;
  gemm_body<128, 128, 0>(A, wt, o, nullptr, nullptr, (z == 0) ? qscale : 1.0f, blockIdx.x);
}

__global__ __launch_bounds__(256) void k_fc1(
    const u16* __restrict__ A, const u16* __restrict__ wt,
    u16* __restrict__ o, const float* __restrict__ bias)
{
  gemm_body<128, 256, 1>(A, wt, o, bias, nullptr, 1.f, blockIdx.x);
}

__global__ __launch_bounds__(256) void k_fc2(
    const u16* __restrict__ A, const u16* __restrict__ wt,
    float* __restrict__ o, const float* __restrict__ bias, const float* __restrict__ res)
{
  gemm_body<256, 128, 2>(A, wt, o, bias, res, 1.f, blockIdx.x);
}

// ------------------------------------------------------------------
// V transpose + prescale by 1/colsum: Vb[m][c] -> Vt[c][m] * (1/colsum[m])
// ------------------------------------------------------------------
__global__ __launch_bounds__(256) void k_trv(
    const u16* __restrict__ in, const float* __restrict__ csum, u16* __restrict__ out)
{
  __shared__ u16 tile[32][33];
  const int b = blockIdx.z;
  const int r0 = blockIdx.x * 32, c0 = blockIdx.y * 32;
  const u16* ib = in + (size_t)b * 819200;
  u16* ob = out + (size_t)b * 819200;
  const int lx = threadIdx.x & 31, ly = threadIdx.x >> 5;
#pragma unroll
  for (int i = 0; i < 4; i++) {
    int r = ly + i * 8;
    tile[r][lx] = ib[(size_t)(r0 + r) * 128 + (c0 + lx)];
  }
  __syncthreads();
  const float rcs = 1.f / csum[(size_t)b * 6400 + r0 + lx];
#pragma unroll
  for (int i = 0; i < 4; i++) {
    int r = ly + i * 8;
    ob[(size_t)(c0 + r) * 6400 + (r0 + lx)] = f2bf(bf2f(tile[lx][r]) * rcs);
  }
}

__global__ __launch_bounds__(256) void k_tr_f32(const float* __restrict__ in, float* __restrict__ out)
{
  __shared__ float tile[32][33];
  const int b = blockIdx.z;
  const int r0 = blockIdx.x * 32, c0 = blockIdx.y * 32;
  const float* ib = in + (size_t)b * 819200;
  float* ob = out + (size_t)b * 819200;
  const int lx = threadIdx.x & 31, ly = threadIdx.x >> 5;
#pragma unroll
  for (int i = 0; i < 4; i++) {
    int r = ly + i * 8;
    tile[r][lx] = ib[(size_t)(r0 + r) * 128 + c0 + lx];
  }
  __syncthreads();
#pragma unroll
  for (int i = 0; i < 4; i++) {
    int r = ly + i * 8;
    ob[(size_t)(c0 + r) * 6400 + r0 + lx] = tile[lx][r];
  }
}

// ------------------------------------------------------------------
// Phase A (R11-verified): colsum + P[n][m] = bf16(2^s) store.
// grid (50 m-blocks, 16 n-splits, 2 batch), block 256
// ------------------------------------------------------------------
__global__ __launch_bounds__(256) void k_phasea(
    const u16* __restrict__ Qb, const u16* __restrict__ Kb, float* __restrict__ colsum,
    u16* __restrict__ P)
{
  constexpr int PS = 272;
  __shared__ alignas(16) char sK[128 * PS];
  __shared__ alignas(16) char sQ[64 * PS];
  const int t = threadIdx.x;
  const int mb = blockIdx.x, split = blockIdx.y, b = blockIdx.z;
  {
    const uint4* g = (const uint4*)(Kb + ((size_t)b * 6400 + mb * 128) * 128);
    for (int i = t; i < 128 * 16; i += 256) {
      int r = i >> 4, s = i & 15;
      *(uint4*)(sK + r * PS + s * 16) = g[i];
    }
  }
  const int w = t >> 6, l = t & 63, lr = l & 15, lg = l >> 4;
  const int col0 = w * 32;
  const int tile0 = split * 6 + (split < 4 ? split : 4);
  const int ntile = 6 + (split < 4 ? 1 : 0);
  u16* Pbb = P ? (P + (size_t)b * 40960000) : nullptr;
  float cs0 = 0.f, cs1 = 0.f;
  for (int tt = 0; tt < ntile; tt++) {
    __syncthreads();
    {
      const uint4* g = (const uint4*)(Qb + ((size_t)b * 6400 + (tile0 + tt) * 64) * 128);
      for (int i = t; i < 64 * 16; i += 256) {
        int r = i >> 4, s = i & 15;
        *(uint4*)(sQ + r * PS + s * 16) = g[i];
      }
    }
    __syncthreads();
    f32x4 acc[4][2] = {};
#pragma unroll
    for (int ks = 0; ks < 4; ks++) {
      const int koff = ks * 64 + lg * 16;
      bf16x8 a[4], bb[2];
#pragma unroll
      for (int rf = 0; rf < 4; rf++)
        a[rf] = *(const bf16x8*)(sQ + (rf * 16 + lr) * PS + koff);
#pragma unroll
      for (int cf = 0; cf < 2; cf++)
        bb[cf] = *(const bf16x8*)(sK + (col0 + cf * 16 + lr) * PS + koff);
#pragma unroll
      for (int rf = 0; rf < 4; rf++)
#pragma unroll
        for (int cf = 0; cf < 2; cf++)
          acc[rf][cf] = __builtin_amdgcn_mfma_f32_16x16x32_bf16(a[rf], bb[cf], acc[rf][cf], 0, 0, 0);
    }
    const int nbase = (tile0 + tt) * 64;
#pragma unroll
    for (int rf = 0; rf < 4; rf++) {
#pragma unroll
      for (int cf = 0; cf < 2; cf++) {
#pragma unroll
        for (int r = 0; r < 4; r++) {
          float e = __builtin_amdgcn_exp2f(acc[rf][cf][r]);
          if (Pbb) {
            const int n = nbase + rf * 16 + lg * 4 + r;
            const int m = mb * 128 + col0 + cf * 16 + lr;
            Pbb[(size_t)n * 6400 + m] = f2bf(e);
          }
          if (cf == 0) cs0 += e; else cs1 += e;
        }
      }
    }
  }
  cs0 += __shfl_xor(cs0, 16); cs0 += __shfl_xor(cs0, 32);
  cs1 += __shfl_xor(cs1, 16); cs1 += __shfl_xor(cs1, 32);
  if (l < 16) {
    float* base = colsum + (size_t)b * 6400 + mb * 128 + col0;
    atomicAdd(base + l, cs0);
    atomicAdd(base + 16 + l, cs1);
  }
}

// ------------------------------------------------------------------
// k_pv: attn[b][n][c] += sum_m P[b][n][m] * V't[b][c][m]
// m-chunk 128 per iteration (gemm_body's verified KDIM=128 inner
// structure: PS=272, KSTEPS=4), staging addresses = R11-verified
// stride-6400 pattern. grid (100 nb, 5 msplit, 2 b), block 256.
// ------------------------------------------------------------------
__global__ __launch_bounds__(256) void k_pv(
    const u16* __restrict__ P, const u16* __restrict__ Vt, float* __restrict__ attn)
{
  constexpr int PR = 272;
  __shared__ alignas(16) char As[64 * PR];
  __shared__ alignas(16) char Bs[128 * PR];
  const int t = threadIdx.x;
  const int nb = blockIdx.x, split = blockIdx.y, b = blockIdx.z;
  const int w = t >> 6, l = t & 63, lr = l & 15, lg = l >> 4;
  const u16* Pb = P + (size_t)b * 40960000 + (size_t)(nb * 64) * 6400;
  const u16* Vtb = Vt + (size_t)b * 819200;
  f32x4 acc[4][2] = {};
  for (int it = 0; it < 10; it++) {
    const int m0 = (split * 10 + it) * 128;
    __syncthreads();
    for (int i = t; i < 1024; i += 256) {
      int r = i >> 4, s = i & 15;
      *(uint4*)(As + r * PR + s * 16) = *(const uint4*)(Pb + (size_t)r * 6400 + m0 + s * 8);
    }
    for (int i = t; i < 2048; i += 256) {
      int r = i >> 4, s = i & 15;
      *(uint4*)(Bs + r * PR + s * 16) = *(const uint4*)(Vtb + (size_t)r * 6400 + m0 + s * 8);
    }
    __syncthreads();
#pragma unroll
    for (int ks = 0; ks < 4; ks++) {
      const int koff = ks * 64 + lg * 16;
      bf16x8 av[4], bv[2];
#pragma unroll
      for (int nf = 0; nf < 4; nf++)
        av[nf] = *(const bf16x8*)(As + (nf * 16 + lr) * PR + koff);
#pragma unroll
      for (int cf = 0; cf < 2; cf++)
        bv[cf] = *(const bf16x8*)(Bs + (w * 32 + cf * 16 + lr) * PR + koff);
#pragma unroll
      for (int nf = 0; nf < 4; nf++)
#pragma unroll
        for (int cf = 0; cf < 2; cf++)
          acc[nf][cf] = __builtin_amdgcn_mfma_f32_16x16x32_bf16(av[nf], bv[cf], acc[nf][cf], 0, 0, 0);
    }
  }
  float* ab = attn + (size_t)b * 819200;
#pragma unroll
  for (int nf = 0; nf < 4; nf++)
#pragma unroll
    for (int cf = 0; cf < 2; cf++)
#pragma unroll
      for (int r = 0; r < 4; r++) {
        const int row = nb * 64 + nf * 16 + lg * 4 + r;
        const int col = w * 32 + cf * 16 + lr;
        atomicAdd(&ab[(size_t)row * 128 + col], acc[nf][cf][r]);
      }
}

// ------------------------------------------------------------------
// Phase B (R3/R7-verified, fallback when ws too small for P)
// ------------------------------------------------------------------
__global__ __launch_bounds__(256) void k_phaseb(
    const u16* __restrict__ Qb, const u16* __restrict__ Kb, const u16* __restrict__ Vt,
    float* __restrict__ attn)
{
  constexpr int PP = 144;
  __shared__ alignas(16) char sP[2][64 * PP];
  const int t = threadIdx.x;
  const int nb = blockIdx.x, split = blockIdx.y, b = blockIdx.z;
  const int w = t >> 6, l = t & 63, lr = l & 15, lg = l >> 4;

  bf16x8 qreg[4][4];
  {
    const u16* Qrow = Qb + ((size_t)b * 6400 + nb * 64) * 128;
#pragma unroll
    for (int cf = 0; cf < 4; cf++)
#pragma unroll
      for (int ks = 0; ks < 4; ks++)
        qreg[cf][ks] = *(const bf16x8*)(Qrow + (size_t)(cf * 16 + lr) * 128 + ks * 32 + lg * 8);
  }

  const u16* Kbb = Kb + (size_t)b * 819200;
  const u16* Vtb = Vt + (size_t)b * 819200;
  f32x4 apv[4][2] = {};
  const int mt0 = (split * 100) / 8, mt1 = ((split + 1) * 100) / 8;
  int p = 0;
  for (int mt = mt0; mt < mt1; mt++) {
    const int m0 = mt * 64;
    bf16x8 vreg[2][2];
#pragma unroll
    for (int cf = 0; cf < 2; cf++)
#pragma unroll
      for (int ks = 0; ks < 2; ks++)
        vreg[cf][ks] = *(const bf16x8*)(Vtb + (size_t)(w * 32 + cf * 16 + lr) * 6400 + m0 + ks * 32 + lg * 8);

    f32x4 as[4] = {};
#pragma unroll
    for (int ks = 0; ks < 4; ks++) {
      bf16x8 af = *(const bf16x8*)(Kbb + (size_t)(m0 + w * 16 + lr) * 128 + ks * 32 + lg * 8);
#pragma unroll
      for (int cf = 0; cf < 4; cf++)
        as[cf] = __builtin_amdgcn_mfma_f32_16x16x32_bf16(af, qreg[cf][ks], as[cf], 0, 0, 0);
    }
    char* sPp = sP[p];
#pragma unroll
    for (int cf = 0; cf < 4; cf++) {
      u32 p0 = pk2(__builtin_amdgcn_exp2f(as[cf][0]), __builtin_amdgcn_exp2f(as[cf][1]));
      u32 p1 = pk2(__builtin_amdgcn_exp2f(as[cf][2]), __builtin_amdgcn_exp2f(as[cf][3]));
      *(uint2*)(sPp + (cf * 16 + lr) * PP + (w * 16 + lg * 4) * 2) = make_uint2(p0, p1);
    }
    __syncthreads();
#pragma unroll
    for (int ks = 0; ks < 2; ks++) {
#pragma unroll
      for (int nf = 0; nf < 4; nf++) {
        bf16x8 av = *(const bf16x8*)(sPp + (nf * 16 + lr) * PP + ks * 64 + lg * 16);
#pragma unroll
        for (int cf = 0; cf < 2; cf++)
          apv[nf][cf] = __builtin_amdgcn_mfma_f32_16x16x32_bf16(av, vreg[cf][ks], apv[nf][cf], 0, 0, 0);
      }
    }
    p ^= 1;
  }
  float* ab = attn + (size_t)b * 6400 * 128;
#pragma unroll
  for (int nf = 0; nf < 4; nf++)
#pragma unroll
    for (int cf = 0; cf < 2; cf++)
#pragma unroll
      for (int r = 0; r < 4; r++) {
        const int row = nb * 64 + nf * 16 + lg * 4 + r;
        const int col = w * 32 + cf * 16 + lr;
        atomicAdd(&ab[(size_t)row * 128 + col], apv[nf][cf][r]);
      }
}

// ------------------------------------------------------------------
extern "C" void kernel_launch(void* const* d_in, const int* in_sizes, int n_in,
                              void* d_out, int out_size, void* d_ws, size_t ws_size,
                              hipStream_t stream)
{
  (void)in_sizes; (void)n_in; (void)out_size;
  const float* x      = (const float*)d_in[0];
  const float* conv0w = (const float*)d_in[1];
  const float* bn_g   = (const float*)d_in[2];
  const float* bn_b   = (const float*)d_in[3];
  const float* ln1_g  = (const float*)d_in[4];
  const float* ln1_b  = (const float*)d_in[5];
  const float* wq     = (const float*)d_in[6];
  const float* wk     = (const float*)d_in[7];
  const float* wv     = (const float*)d_in[8];
  const float* ln2_g  = (const float*)d_in[9];
  const float* ln2_b  = (const float*)d_in[10];
  const float* fc1_w  = (const float*)d_in[11];
  const float* fc1_b  = (const float*)d_in[12];
  const float* fc2_w  = (const float*)d_in[13];
  const float* fc2_b  = (const float*)d_in[14];

  char* ws = (char*)d_ws;
  size_t off = 0;
  auto alloc = [&](size_t sz) -> void* {
    void* p = ws + off;
    off = (off + sz + 255) & ~(size_t)255;
    return p;
  };
  float* t0   = (float*)alloc((size_t)2 * 6400 * 128 * 4);
  u16* ln1o   = (u16*)alloc((size_t)2 * 6400 * 128 * 2);
  u16* Qb     = (u16*)alloc((size_t)2 * 6400 * 128 * 2);
  u16* Kb     = (u16*)alloc((size_t)2 * 6400 * 128 * 2);
  u16* Vb     = (u16*)alloc((size_t)2 * 6400 * 128 * 2);
  u16* Vtb    = (u16*)alloc((size_t)2 * 6400 * 128 * 2);
  float* csum = (float*)alloc((size_t)2 * 6400 * 4);
  float* attn = (float*)alloc((size_t)2 * 6400 * 128 * 4);
  u16* m1     = (u16*)alloc((size_t)2 * 6400 * 256 * 2);
  u16* wT     = (u16*)alloc((size_t)3 * 128 * 128 * 2);
  u16* fc1t   = (u16*)alloc((size_t)256 * 128 * 2);
  u16* fc2t   = (u16*)alloc((size_t)128 * 256 * 2);
  u16* P      = (u16*)alloc((size_t)2 * 6400 * 6400 * 2);
  const bool useP = (off <= ws_size);

  // qscale = log2(e) / sqrt(128)  -> exp2 in both attention phases
  const float qscale = (float)(1.4426950408889634 * 0.08838834764831845);

  hipMemsetAsync(csum, 0, (size_t)2 * 6400 * 4, stream);
  k_wconv_qkv<<<dim3(64, 3, 1), 256, 0, stream>>>(wq, wk, wv, wT);
  k_wt<<<128, 256, 0, stream>>>(fc1_w, fc1t, 128, 256);
  k_wt<<<128, 256, 0, stream>>>(fc2_w, fc2t, 256, 128);
  // conv writes to both t0 and attn (residual base) — no D2D memcpy needed
  k_conv<<<dim3(25, 8, 2), 256, 0, stream>>>(x, conv0w, bn_g, bn_b, t0, attn);
  k_ln<<<3200, 256, 0, stream>>>(t0, ln1_g, ln1_b, ln1o);
  k_qkv<<<dim3(200, 3, 1), 256, 0, stream>>>(ln1o, wT, Qb, Kb, Vb, qscale);
  k_phasea<<<dim3(50, 16, 2), 256, 0, stream>>>(Qb, Kb, csum, useP ? P : nullptr);
  k_trv<<<dim3(200, 4, 2), 256, 0, stream>>>(Vb, csum, Vtb);
  if (useP)
    k_pv<<<dim3(100, 5, 2), 256, 0, stream>>>(P, Vtb, attn);
  else
    k_phaseb<<<dim3(100, 8, 2), 256, 0, stream>>>(Qb, Kb, Vtb, attn);
  k_ln<<<3200, 256, 0, stream>>>(attn, ln2_g, ln2_b, ln1o);
  k_fc1<<<200, 256, 0, stream>>>(ln1o, fc1t, m1, fc1_b);
  k_fc2<<<200, 256, 0, stream>>>(m1, fc2t, t0, fc2_b, attn);
  k_tr_f32<<<dim3(200, 4, 2), 256, 0, stream>>>(t0, (float*)d_out);
}

// Round 13
// 227.542 us; speedup vs baseline: 1.0647x; 1.0647x over previous
//
#include <hip/hip_runtime.h>
#include <hip/hip_bf16.h>
#include <math.h>

typedef unsigned int u32;
typedef unsigned short u16;
typedef __attribute__((ext_vector_type(4))) float f32x4;
typedef __attribute__((ext_vector_type(8))) short bf16x8;

#define DEV __device__ __forceinline__

DEV u16 f2bf(float f) {
  union { float f; u32 u; } v; v.f = f;
  u32 u = v.u;
  return (u16)((u + 0x7FFFu + ((u >> 16) & 1u)) >> 16);
}

DEV float bf2f(u16 h) {
  union { u32 u; float f; } v; v.u = (u32)h << 16;
  return v.f;
}

// v_cvt_pk_bf16_f32: lo = bf16(a), hi = bf16(b) (RNE)
DEV u32 pk2(float a, float b) {
  u32 r;
  asm("v_cvt_pk_bf16_f32 %0, %1, %2" : "=v"(r) : "v"(a), "v"(b));
  return r;
}

// ------------------------------------------------------------------
// Conv 5x5 (9->128) + BN(eval) + LeakyReLU(0.2) + 2D pos-enc
// Writes result to BOTH t0 (LN input) and attn (residual base).
// ------------------------------------------------------------------
__global__ __launch_bounds__(256) void k_conv(
    const float* __restrict__ x, const float* __restrict__ cw,
    const float* __restrict__ bng, const float* __restrict__ bnb,
    float* __restrict__ t0, float* __restrict__ attn)
{
  __shared__ float sinp[9 * 400];
  __shared__ float sw[225 * 16];
  const int t = threadIdx.x;
  const int tile = blockIdx.x, cg = blockIdx.y, b = blockIdx.z;
  const int ty0 = (tile / 5) * 16, tx0 = (tile % 5) * 16;

  for (int i = t; i < 3600; i += 256) {
    int ci = i / 400, rem = i % 400, r = rem / 20, cc = rem % 20;
    int gy = ty0 + r - 2, gx = tx0 + cc - 2;
    float v = 0.f;
    if ((unsigned)gy < 80u && (unsigned)gx < 80u) {
      int c = ci % 3, tt = ci / 3;
      v = x[(((size_t)b * 3 + c) * 3 + tt) * 6400 + gy * 80 + gx];
    }
    sinp[i] = v;
  }
  for (int i = t; i < 3600; i += 256) {
    int c = i & 15, j = i >> 4;
    sw[i] = cw[(size_t)(cg * 16 + c) * 225 + j];
  }
  __syncthreads();

  const int lx = t & 15, ly = t >> 4;
  float acc[16];
#pragma unroll
  for (int c = 0; c < 16; c++) acc[c] = 0.f;

  for (int ci = 0; ci < 9; ci++) {
#pragma unroll
    for (int ky = 0; ky < 5; ky++) {
      const float* ro = &sinp[ci * 400 + (ly + ky) * 20 + lx];
#pragma unroll
      for (int kx = 0; kx < 5; kx++) {
        float v = ro[kx];
        const float4* w4 = (const float4*)&sw[(ci * 25 + ky * 5 + kx) * 16];
        float4 w0 = w4[0], w1 = w4[1], w2 = w4[2], w3 = w4[3];
        acc[0] += v * w0.x;  acc[1] += v * w0.y;  acc[2] += v * w0.z;  acc[3] += v * w0.w;
        acc[4] += v * w1.x;  acc[5] += v * w1.y;  acc[6] += v * w1.z;  acc[7] += v * w1.w;
        acc[8] += v * w2.x;  acc[9] += v * w2.y;  acc[10] += v * w2.z; acc[11] += v * w2.w;
        acc[12] += v * w3.x; acc[13] += v * w3.y; acc[14] += v * w3.z; acc[15] += v * w3.w;
      }
    }
  }

  const int gy = ty0 + ly, gx = tx0 + lx;
  const int n = gy * 80 + gx;
  const float rb = rsqrtf(1.f + 1e-5f);
  const float NEG_L = -logf(10000.f) / 32.f;
  float outv[16];
#pragma unroll
  for (int c = 0; c < 16; c++) {
    int co = cg * 16 + c;
    float v = acc[c] * rb * bng[co] + bnb[co];
    v = v > 0.f ? v : 0.2f * v;
    int j = (co < 64) ? co : co - 64;
    float pos = (co < 64) ? (float)gy : (float)gx;
    int k = j & 31;
    float ang = pos * __expf((float)k * NEG_L);
    v += (j < 32) ? __sinf(ang) : __cosf(ang);
    outv[c] = v;
  }
  const size_t base = ((size_t)b * 6400 + n) * 128 + cg * 16;
  float4* dst = (float4*)&t0[base];
  float4* dst2 = (float4*)&attn[base];
  const float4* src = (const float4*)outv;
  dst[0] = src[0]; dst[1] = src[1]; dst[2] = src[2]; dst[3] = src[3];
  dst2[0] = src[0]; dst2[1] = src[1]; dst2[2] = src[2]; dst2[3] = src[3];
}

// ------------------------------------------------------------------
// LayerNorm over last dim (128), fp32 in -> bf16 out. 1 wave = 1 token.
// ------------------------------------------------------------------
__global__ __launch_bounds__(256) void k_ln(
    const float* __restrict__ X, const float* __restrict__ g,
    const float* __restrict__ bta, u16* __restrict__ O)
{
  const int w = threadIdx.x >> 6, l = threadIdx.x & 63;
  const int tok = blockIdx.x * 4 + w;
  const float2 v = ((const float2*)(X + (size_t)tok * 128))[l];
  float s = v.x + v.y;
#pragma unroll
  for (int m = 1; m < 64; m <<= 1) s += __shfl_xor(s, m);
  const float mean = s * (1.f / 128.f);
  const float dx = v.x - mean, dy = v.y - mean;
  float q = dx * dx + dy * dy;
#pragma unroll
  for (int m = 1; m < 64; m <<= 1) q += __shfl_xor(q, m);
  const float rstd = rsqrtf(q * (1.f / 128.f) + 1e-5f);
  const float2 gg = ((const float2*)g)[l];
  const float2 bb = ((const float2*)bta)[l];
  const float o0 = dx * rstd * gg.x + bb.x;
  const float o1 = dy * rstd * gg.y + bb.y;
  ((u32*)O)[(size_t)tok * 64 + l] = (u32)f2bf(o0) | ((u32)f2bf(o1) << 16);
}

// ------------------------------------------------------------------
// Weight convert/transpose: fp32 [K][N] -> bf16 [N][K]
// ------------------------------------------------------------------
__global__ __launch_bounds__(256) void k_wconv_qkv(
    const float* __restrict__ wq, const float* __restrict__ wk,
    const float* __restrict__ wv, u16* __restrict__ o)
{
  const int z = blockIdx.y;
  const float* in = (z == 0) ? wq : (z == 1) ? wk : wv;
  u16* out = o + (size_t)z * 16384;
  const int i = blockIdx.x * 256 + threadIdx.x;
  const int n = i & 127, k = i >> 7;
  out[n * 128 + k] = f2bf(in[i]);
}

__global__ __launch_bounds__(256) void k_wt(
    const float* __restrict__ in, u16* __restrict__ out, int K, int N)
{
  const int i = blockIdx.x * 256 + threadIdx.x;
  if (i >= K * N) return;
  const int n = i % N, k = i / N;
  out[n * K + k] = f2bf(in[i]);
}

// ------------------------------------------------------------------
// Generic MFMA GEMM body
// ------------------------------------------------------------------
template <int KDIM, int NTILE, int EPI>
DEV void gemm_body(const u16* __restrict__ A, const u16* __restrict__ WT,
                   void* __restrict__ OUT, const float* __restrict__ bias,
                   const float* __restrict__ res, float scale, int bm)
{
  constexpr int PS = KDIM * 2 + 16;
  constexpr int KSTEPS = KDIM / 32;
  constexpr int CF = NTILE / 64;
  constexpr int CPR = KDIM * 2 / 16;
  __shared__ alignas(16) char As[64 * PS];
  __shared__ alignas(16) char Ws[NTILE * PS];
  const int t = threadIdx.x;
  {
    const uint4* g = (const uint4*)(A + (size_t)bm * 64 * KDIM);
    for (int i = t; i < 64 * CPR; i += 256) {
      int r = i / CPR, s = i - r * CPR;
      *(uint4*)(As + r * PS + s * 16) = g[i];
    }
    const uint4* gw = (const uint4*)WT;
    for (int i = t; i < NTILE * CPR; i += 256) {
      int r = i / CPR, s = i - r * CPR;
      *(uint4*)(Ws + r * PS + s * 16) = gw[i];
    }
  }
  __syncthreads();
  const int w = t >> 6, l = t & 63, lr = l & 15, lg = l >> 4;
  const int col0 = w * (NTILE / 4);
  f32x4 acc[4][CF] = {};
#pragma unroll
  for (int ks = 0; ks < KSTEPS; ks++) {
    const int koff = ks * 64 + lg * 16;
    bf16x8 a[4], bfr[CF];
#pragma unroll
    for (int rf = 0; rf < 4; rf++)
      a[rf] = *(const bf16x8*)(As + (rf * 16 + lr) * PS + koff);
#pragma unroll
    for (int cf = 0; cf < CF; cf++)
      bfr[cf] = *(const bf16x8*)(Ws + (col0 + cf * 16 + lr) * PS + koff);
#pragma unroll
    for (int rf = 0; rf < 4; rf++)
#pragma unroll
      for (int cf = 0; cf < CF; cf++)
        acc[rf][cf] = __builtin_amdgcn_mfma_f32_16x16x32_bf16(a[rf], bfr[cf], acc[rf][cf], 0, 0, 0);
  }
#pragma unroll
  for (int rf = 0; rf < 4; rf++) {
#pragma unroll
    for (int cf = 0; cf < CF; cf++) {
#pragma unroll
      for (int r = 0; r < 4; r++) {
        const int row = bm * 64 + rf * 16 + lg * 4 + r;
        const int col = col0 + cf * 16 + lr;
        float v = acc[rf][cf][r] * scale;
        if (EPI == 0) {
          ((u16*)OUT)[(size_t)row * NTILE + col] = f2bf(v);
        } else if (EPI == 1) {
          v += bias[col];
          v = 0.5f * v * (1.f + erff(v * 0.70710678118654752f));
          ((u16*)OUT)[(size_t)row * NTILE + col] = f2bf(v);
        } else {
          v += bias[col] + res[(size_t)row * NTILE + col];
          ((float*)OUT)[(size_t)row * NTILE + col] = v;
        }
      }
    }
  }
}

__global__ __launch_bounds__(256) void k_qkv(
    const u16* __restrict__ A, const u16* __restrict__ wT,
    u16* __restrict__ Q, u16* __restrict__ K, u16* __restrict__ V, float qscale)
{
  const int z = blockIdx.y;
  const u16* wt = wT + (size_t)z * 16384;
  u16* o = (z == 0) ? Q : (z == 1) ? K : V;
  gemm_body<128, 128, 0>(A, wt, o, nullptr, nullptr, (z == 0) ? qscale : 1.0f, blockIdx.x);
}

__global__ __launch_bounds__(256) void k_fc1(
    const u16* __restrict__ A, const u16* __restrict__ wt,
    u16* __restrict__ o, const float* __restrict__ bias)
{
  gemm_body<128, 256, 1>(A, wt, o, bias, nullptr, 1.f, blockIdx.x);
}

__global__ __launch_bounds__(256) void k_fc2(
    const u16* __restrict__ A, const u16* __restrict__ wt,
    float* __restrict__ o, const float* __restrict__ bias, const float* __restrict__ res)
{
  gemm_body<256, 128, 2>(A, wt, o, bias, res, 1.f, blockIdx.x);
}

// ------------------------------------------------------------------
// V transpose + prescale by 1/colsum: Vb[m][c] -> Vt[c][m] * (1/colsum[m])
// ------------------------------------------------------------------
__global__ __launch_bounds__(256) void k_trv(
    const u16* __restrict__ in, const float* __restrict__ csum, u16* __restrict__ out)
{
  __shared__ u16 tile[32][33];
  const int b = blockIdx.z;
  const int r0 = blockIdx.x * 32, c0 = blockIdx.y * 32;
  const u16* ib = in + (size_t)b * 819200;
  u16* ob = out + (size_t)b * 819200;
  const int lx = threadIdx.x & 31, ly = threadIdx.x >> 5;
#pragma unroll
  for (int i = 0; i < 4; i++) {
    int r = ly + i * 8;
    tile[r][lx] = ib[(size_t)(r0 + r) * 128 + (c0 + lx)];
  }
  __syncthreads();
  const float rcs = 1.f / csum[(size_t)b * 6400 + r0 + lx];
#pragma unroll
  for (int i = 0; i < 4; i++) {
    int r = ly + i * 8;
    ob[(size_t)(c0 + r) * 6400 + (r0 + lx)] = f2bf(bf2f(tile[lx][r]) * rcs);
  }
}

__global__ __launch_bounds__(256) void k_tr_f32(const float* __restrict__ in, float* __restrict__ out)
{
  __shared__ float tile[32][33];
  const int b = blockIdx.z;
  const int r0 = blockIdx.x * 32, c0 = blockIdx.y * 32;
  const float* ib = in + (size_t)b * 819200;
  float* ob = out + (size_t)b * 819200;
  const int lx = threadIdx.x & 31, ly = threadIdx.x >> 5;
#pragma unroll
  for (int i = 0; i < 4; i++) {
    int r = ly + i * 8;
    tile[r][lx] = ib[(size_t)(r0 + r) * 128 + c0 + lx];
  }
  __syncthreads();
#pragma unroll
  for (int i = 0; i < 4; i++) {
    int r = ly + i * 8;
    ob[(size_t)(c0 + r) * 6400 + r0 + lx] = tile[lx][r];
  }
}

// ------------------------------------------------------------------
// Phase A (R11-verified): colsum + P[n][m] = bf16(2^s) store.
// grid (50 m-blocks, 16 n-splits, 2 batch), block 256
// ------------------------------------------------------------------
__global__ __launch_bounds__(256) void k_phasea(
    const u16* __restrict__ Qb, const u16* __restrict__ Kb, float* __restrict__ colsum,
    u16* __restrict__ P)
{
  constexpr int PS = 272;
  __shared__ alignas(16) char sK[128 * PS];
  __shared__ alignas(16) char sQ[64 * PS];
  const int t = threadIdx.x;
  const int mb = blockIdx.x, split = blockIdx.y, b = blockIdx.z;
  {
    const uint4* g = (const uint4*)(Kb + ((size_t)b * 6400 + mb * 128) * 128);
    for (int i = t; i < 128 * 16; i += 256) {
      int r = i >> 4, s = i & 15;
      *(uint4*)(sK + r * PS + s * 16) = g[i];
    }
  }
  const int w = t >> 6, l = t & 63, lr = l & 15, lg = l >> 4;
  const int col0 = w * 32;
  const int tile0 = split * 6 + (split < 4 ? split : 4);
  const int ntile = 6 + (split < 4 ? 1 : 0);
  u16* Pbb = P ? (P + (size_t)b * 40960000) : nullptr;
  float cs0 = 0.f, cs1 = 0.f;
  for (int tt = 0; tt < ntile; tt++) {
    __syncthreads();
    {
      const uint4* g = (const uint4*)(Qb + ((size_t)b * 6400 + (tile0 + tt) * 64) * 128);
      for (int i = t; i < 64 * 16; i += 256) {
        int r = i >> 4, s = i & 15;
        *(uint4*)(sQ + r * PS + s * 16) = g[i];
      }
    }
    __syncthreads();
    f32x4 acc[4][2] = {};
#pragma unroll
    for (int ks = 0; ks < 4; ks++) {
      const int koff = ks * 64 + lg * 16;
      bf16x8 a[4], bb[2];
#pragma unroll
      for (int rf = 0; rf < 4; rf++)
        a[rf] = *(const bf16x8*)(sQ + (rf * 16 + lr) * PS + koff);
#pragma unroll
      for (int cf = 0; cf < 2; cf++)
        bb[cf] = *(const bf16x8*)(sK + (col0 + cf * 16 + lr) * PS + koff);
#pragma unroll
      for (int rf = 0; rf < 4; rf++)
#pragma unroll
        for (int cf = 0; cf < 2; cf++)
          acc[rf][cf] = __builtin_amdgcn_mfma_f32_16x16x32_bf16(a[rf], bb[cf], acc[rf][cf], 0, 0, 0);
    }
    const int nbase = (tile0 + tt) * 64;
#pragma unroll
    for (int rf = 0; rf < 4; rf++) {
#pragma unroll
      for (int cf = 0; cf < 2; cf++) {
#pragma unroll
        for (int r = 0; r < 4; r++) {
          float e = __builtin_amdgcn_exp2f(acc[rf][cf][r]);
          if (Pbb) {
            const int n = nbase + rf * 16 + lg * 4 + r;
            const int m = mb * 128 + col0 + cf * 16 + lr;
            Pbb[(size_t)n * 6400 + m] = f2bf(e);
          }
          if (cf == 0) cs0 += e; else cs1 += e;
        }
      }
    }
  }
  cs0 += __shfl_xor(cs0, 16); cs0 += __shfl_xor(cs0, 32);
  cs1 += __shfl_xor(cs1, 16); cs1 += __shfl_xor(cs1, 32);
  if (l < 16) {
    float* base = colsum + (size_t)b * 6400 + mb * 128 + col0;
    atomicAdd(base + l, cs0);
    atomicAdd(base + 16 + l, cs1);
  }
}

// ------------------------------------------------------------------
// k_pv (R11-verified body, m-chunk 64): attn += sum_m P[n][m] * V't[c][m]
// Only change vs R11: msplit 4 -> 5 (pure range split; 20 iters),
// grid (100 nb, 5 msplit, 2 b) = 1000 blocks for higher residency.
// ------------------------------------------------------------------
__global__ __launch_bounds__(256) void k_pv(
    const u16* __restrict__ P, const u16* __restrict__ Vt, float* __restrict__ attn)
{
  constexpr int PR = 144;
  __shared__ alignas(16) char As[64 * PR];
  __shared__ alignas(16) char Bs[128 * PR];
  const int t = threadIdx.x;
  const int nb = blockIdx.x, split = blockIdx.y, b = blockIdx.z;
  const int w = t >> 6, l = t & 63, lr = l & 15, lg = l >> 4;
  const u16* Pb = P + (size_t)b * 40960000 + (size_t)(nb * 64) * 6400;
  const u16* Vtb = Vt + (size_t)b * 819200;
  f32x4 acc[4][2] = {};
  for (int it = 0; it < 20; it++) {
    const int m0 = (split * 20 + it) * 64;
    __syncthreads();
    for (int i = t; i < 512; i += 256) {
      int r = i >> 3, s = i & 7;
      *(uint4*)(As + r * PR + s * 16) = *(const uint4*)(Pb + (size_t)r * 6400 + m0 + s * 8);
    }
    for (int i = t; i < 1024; i += 256) {
      int r = i >> 3, s = i & 7;
      *(uint4*)(Bs + r * PR + s * 16) = *(const uint4*)(Vtb + (size_t)r * 6400 + m0 + s * 8);
    }
    __syncthreads();
#pragma unroll
    for (int ks = 0; ks < 2; ks++) {
      const int koff = ks * 64 + lg * 16;
      bf16x8 av[4], bv[2];
#pragma unroll
      for (int nf = 0; nf < 4; nf++)
        av[nf] = *(const bf16x8*)(As + (nf * 16 + lr) * PR + koff);
#pragma unroll
      for (int cf = 0; cf < 2; cf++)
        bv[cf] = *(const bf16x8*)(Bs + (w * 32 + cf * 16 + lr) * PR + koff);
#pragma unroll
      for (int nf = 0; nf < 4; nf++)
#pragma unroll
        for (int cf = 0; cf < 2; cf++)
          acc[nf][cf] = __builtin_amdgcn_mfma_f32_16x16x32_bf16(av[nf], bv[cf], acc[nf][cf], 0, 0, 0);
    }
  }
  float* ab = attn + (size_t)b * 819200;
#pragma unroll
  for (int nf = 0; nf < 4; nf++)
#pragma unroll
    for (int cf = 0; cf < 2; cf++)
#pragma unroll
      for (int r = 0; r < 4; r++) {
        const int row = nb * 64 + nf * 16 + lg * 4 + r;
        const int col = w * 32 + cf * 16 + lr;
        atomicAdd(&ab[(size_t)row * 128 + col], acc[nf][cf][r]);
      }
}

// ------------------------------------------------------------------
// Phase B (R3/R7-verified, fallback when ws too small for P)
// ------------------------------------------------------------------
__global__ __launch_bounds__(256) void k_phaseb(
    const u16* __restrict__ Qb, const u16* __restrict__ Kb, const u16* __restrict__ Vt,
    float* __restrict__ attn)
{
  constexpr int PP = 144;
  __shared__ alignas(16) char sP[2][64 * PP];
  const int t = threadIdx.x;
  const int nb = blockIdx.x, split = blockIdx.y, b = blockIdx.z;
  const int w = t >> 6, l = t & 63, lr = l & 15, lg = l >> 4;

  bf16x8 qreg[4][4];
  {
    const u16* Qrow = Qb + ((size_t)b * 6400 + nb * 64) * 128;
#pragma unroll
    for (int cf = 0; cf < 4; cf++)
#pragma unroll
      for (int ks = 0; ks < 4; ks++)
        qreg[cf][ks] = *(const bf16x8*)(Qrow + (size_t)(cf * 16 + lr) * 128 + ks * 32 + lg * 8);
  }

  const u16* Kbb = Kb + (size_t)b * 819200;
  const u16* Vtb = Vt + (size_t)b * 819200;
  f32x4 apv[4][2] = {};
  const int mt0 = (split * 100) / 8, mt1 = ((split + 1) * 100) / 8;
  int p = 0;
  for (int mt = mt0; mt < mt1; mt++) {
    const int m0 = mt * 64;
    bf16x8 vreg[2][2];
#pragma unroll
    for (int cf = 0; cf < 2; cf++)
#pragma unroll
      for (int ks = 0; ks < 2; ks++)
        vreg[cf][ks] = *(const bf16x8*)(Vtb + (size_t)(w * 32 + cf * 16 + lr) * 6400 + m0 + ks * 32 + lg * 8);

    f32x4 as[4] = {};
#pragma unroll
    for (int ks = 0; ks < 4; ks++) {
      bf16x8 af = *(const bf16x8*)(Kbb + (size_t)(m0 + w * 16 + lr) * 128 + ks * 32 + lg * 8);
#pragma unroll
      for (int cf = 0; cf < 4; cf++)
        as[cf] = __builtin_amdgcn_mfma_f32_16x16x32_bf16(af, qreg[cf][ks], as[cf], 0, 0, 0);
    }
    char* sPp = sP[p];
#pragma unroll
    for (int cf = 0; cf < 4; cf++) {
      u32 p0 = pk2(__builtin_amdgcn_exp2f(as[cf][0]), __builtin_amdgcn_exp2f(as[cf][1]));
      u32 p1 = pk2(__builtin_amdgcn_exp2f(as[cf][2]), __builtin_amdgcn_exp2f(as[cf][3]));
      *(uint2*)(sPp + (cf * 16 + lr) * PP + (w * 16 + lg * 4) * 2) = make_uint2(p0, p1);
    }
    __syncthreads();
#pragma unroll
    for (int ks = 0; ks < 2; ks++) {
#pragma unroll
      for (int nf = 0; nf < 4; nf++) {
        bf16x8 av = *(const bf16x8*)(sPp + (nf * 16 + lr) * PP + ks * 64 + lg * 16);
#pragma unroll
        for (int cf = 0; cf < 2; cf++)
          apv[nf][cf] = __builtin_amdgcn_mfma_f32_16x16x32_bf16(av, vreg[cf][ks], apv[nf][cf], 0, 0, 0);
      }
    }
    p ^= 1;
  }
  float* ab = attn + (size_t)b * 6400 * 128;
#pragma unroll
  for (int nf = 0; nf < 4; nf++)
#pragma unroll
    for (int cf = 0; cf < 2; cf++)
#pragma unroll
      for (int r = 0; r < 4; r++) {
        const int row = nb * 64 + nf * 16 + lg * 4 + r;
        const int col = w * 32 + cf * 16 + lr;
        atomicAdd(&ab[(size_t)row * 128 + col], apv[nf][cf][r]);
      }
}

// ------------------------------------------------------------------
extern "C" void kernel_launch(void* const* d_in, const int* in_sizes, int n_in,
                              void* d_out, int out_size, void* d_ws, size_t ws_size,
                              hipStream_t stream)
{
  (void)in_sizes; (void)n_in; (void)out_size;
  const float* x      = (const float*)d_in[0];
  const float* conv0w = (const float*)d_in[1];
  const float* bn_g   = (const float*)d_in[2];
  const float* bn_b   = (const float*)d_in[3];
  const float* ln1_g  = (const float*)d_in[4];
  const float* ln1_b  = (const float*)d_in[5];
  const float* wq     = (const float*)d_in[6];
  const float* wk     = (const float*)d_in[7];
  const float* wv     = (const float*)d_in[8];
  const float* ln2_g  = (const float*)d_in[9];
  const float* ln2_b  = (const float*)d_in[10];
  const float* fc1_w  = (const float*)d_in[11];
  const float* fc1_b  = (const float*)d_in[12];
  const float* fc2_w  = (const float*)d_in[13];
  const float* fc2_b  = (const float*)d_in[14];

  char* ws = (char*)d_ws;
  size_t off = 0;
  auto alloc = [&](size_t sz) -> void* {
    void* p = ws + off;
    off = (off + sz + 255) & ~(size_t)255;
    return p;
  };
  float* t0   = (float*)alloc((size_t)2 * 6400 * 128 * 4);
  u16* ln1o   = (u16*)alloc((size_t)2 * 6400 * 128 * 2);
  u16* Qb     = (u16*)alloc((size_t)2 * 6400 * 128 * 2);
  u16* Kb     = (u16*)alloc((size_t)2 * 6400 * 128 * 2);
  u16* Vb     = (u16*)alloc((size_t)2 * 6400 * 128 * 2);
  u16* Vtb    = (u16*)alloc((size_t)2 * 6400 * 128 * 2);
  float* csum = (float*)alloc((size_t)2 * 6400 * 4);
  float* attn = (float*)alloc((size_t)2 * 6400 * 128 * 4);
  u16* m1     = (u16*)alloc((size_t)2 * 6400 * 256 * 2);
  u16* wT     = (u16*)alloc((size_t)3 * 128 * 128 * 2);
  u16* fc1t   = (u16*)alloc((size_t)256 * 128 * 2);
  u16* fc2t   = (u16*)alloc((size_t)128 * 256 * 2);
  u16* P      = (u16*)alloc((size_t)2 * 6400 * 6400 * 2);
  const bool useP = (off <= ws_size);

  // qscale = log2(e) / sqrt(128)  -> exp2 in both attention phases
  const float qscale = (float)(1.4426950408889634 * 0.08838834764831845);

  hipMemsetAsync(csum, 0, (size_t)2 * 6400 * 4, stream);
  k_wconv_qkv<<<dim3(64, 3, 1), 256, 0, stream>>>(wq, wk, wv, wT);
  k_wt<<<128, 256, 0, stream>>>(fc1_w, fc1t, 128, 256);
  k_wt<<<128, 256, 0, stream>>>(fc2_w, fc2t, 256, 128);
  // conv writes to both t0 and attn (residual base) — no D2D memcpy needed
  k_conv<<<dim3(25, 8, 2), 256, 0, stream>>>(x, conv0w, bn_g, bn_b, t0, attn);
  k_ln<<<3200, 256, 0, stream>>>(t0, ln1_g, ln1_b, ln1o);
  k_qkv<<<dim3(200, 3, 1), 256, 0, stream>>>(ln1o, wT, Qb, Kb, Vb, qscale);
  k_phasea<<<dim3(50, 16, 2), 256, 0, stream>>>(Qb, Kb, csum, useP ? P : nullptr);
  k_trv<<<dim3(200, 4, 2), 256, 0, stream>>>(Vb, csum, Vtb);
  if (useP)
    k_pv<<<dim3(100, 5, 2), 256, 0, stream>>>(P, Vtb, attn);
  else
    k_phaseb<<<dim3(100, 8, 2), 256, 0, stream>>>(Qb, Kb, Vtb, attn);
  k_ln<<<3200, 256, 0, stream>>>(attn, ln2_g, ln2_b, ln1o);
  k_fc1<<<200, 256, 0, stream>>>(ln1o, fc1t, m1, fc1_b);
  k_fc2<<<200, 256, 0, stream>>>(m1, fc2t, t0, fc2_b, attn);
  k_tr_f32<<<dim3(200, 4, 2), 256, 0, stream>>>(t0, (float*)d_out);
}